// Round 3
// baseline (496.496 us; speedup 1.0000x reference)
//
#include <hip/hip_runtime.h>

typedef _Float16 f16;
typedef __attribute__((ext_vector_type(2))) _Float16 f16x2;
typedef __attribute__((ext_vector_type(4))) _Float16 f16x4;
typedef __attribute__((ext_vector_type(8))) _Float16 f16x8;
typedef __attribute__((ext_vector_type(4))) float fvec4;
typedef __attribute__((ext_vector_type(4))) float f32x4;
typedef __attribute__((ext_vector_type(16))) float f32x16;
typedef __attribute__((ext_vector_type(4))) unsigned int uint4v;

#define NKEY 784
#define NKEYP 800
#define NQ 196
#define NQP 224

static __device__ __forceinline__ f32x4 mfma16(f16x8 a, f16x8 b, f32x4 c) {
    return __builtin_amdgcn_mfma_f32_16x16x32_f16(a, b, c, 0, 0, 0);
}
static __device__ __forceinline__ f32x16 mfma32(f16x8 a, f16x8 b, f32x16 c) {
    return __builtin_amdgcn_mfma_f32_32x32x16_f16(a, b, c, 0, 0, 0);
}
static __device__ __forceinline__ unsigned pk2(float a, float b) {
    f16x2 t; t[0] = (_Float16)a; t[1] = (_Float16)b;
    return __builtin_bit_cast(unsigned, t);
}
static __device__ __forceinline__ f32x16 z16() {
    f32x16 v;
#pragma unroll
    for (int i = 0; i < 16; ++i) v[i] = 0.f;
    return v;
}

// ---------------- prep: fold BN into scale/shift (all three BNs) ----------------
__global__ void prep_scales_all(const float* __restrict__ kg, const float* __restrict__ kb,
                                const float* __restrict__ km, const float* __restrict__ kvv,
                                const float* __restrict__ qg, const float* __restrict__ qb,
                                const float* __restrict__ qm, const float* __restrict__ qv,
                                const float* __restrict__ pg, const float* __restrict__ pb,
                                const float* __restrict__ pm, const float* __restrict__ pv,
                                float* __restrict__ sb) {
    int i = blockIdx.x * 256 + threadIdx.x;
    if (i < 640) {
        float s = kg[i] * rsqrtf(kvv[i] + 1e-5f);
        sb[i] = s; sb[640 + i] = kb[i] - km[i] * s;
    } else if (i < 768) {
        int j = i - 640;
        float s = qg[j] * rsqrtf(qv[j] + 1e-5f);
        sb[1280 + j] = s; sb[1408 + j] = qb[j] - qm[j] * s;
    } else if (i < 1152) {
        int j = i - 768;
        float s = pg[j] * rsqrtf(pv[j] + 1e-5f);
        sb[1536 + j] = s; sb[1920 + j] = pb[j] - pm[j] * s;
    }
}

// ---------------- prep: convert all weights to f16 ----------------
__global__ void conv_w(const float* __restrict__ wkv, const float* __restrict__ wq,
                       const float* __restrict__ wp, f16* __restrict__ out) {
    int i = blockIdx.x * 256 + threadIdx.x;   // 98304 threads, 4 floats each
    const float* src; int off;
    if (i < 40960)      { src = wkv; off = 0; }
    else if (i < 49152) { src = wq;  off = 40960; }
    else                { src = wp;  off = 49152; }
    fvec4 v = *(const fvec4*)(src + (size_t)(i - off) * 4);
    f16x4 h;
#pragma unroll
    for (int j = 0; j < 4; ++j) h[j] = (f16)v[j];
    *(f16x4*)(out + (size_t)i * 4) = h;
}

// ---------------- prep: gather bias f16 [h][q(224)][key(800)] ----------------
__global__ void prep_bias(const float* __restrict__ biases, const int* __restrict__ idxs,
                          f16* __restrict__ biasT, int n_off) {
    int tid = blockIdx.x * 256 + threadIdx.x;   // 8*224*800
    int h = tid / (NQP * NKEYP);
    int rem = tid - h * (NQP * NKEYP);
    int q = rem / NKEYP;
    int key = rem - q * NKEYP;
    float v = 0.f;
    if (q < NQ && key < NKEY) v = biases[h * n_off + idxs[q * NKEY + key]];
    biasT[tid] = (f16)v;
}

// ---------------- register-A-resident GEMM + BN epilogue (no LDS) ----------------
// MODE 0: kv  : A f32 [100352][256] -> K f16 [1024][800][16] + V^T f16 [1024][64][800]
// MODE 1: q   : A f32 subsampled   -> q f16 [1024][224][16]
// MODE 2: proj: A f16 [25088][512] -> out f32 [25088][384]
template <int MODE>
__global__ __launch_bounds__(256) void gemm_reg(const void* __restrict__ Ap,
                                                const f16* __restrict__ Wf,
                                                const float* __restrict__ sc,
                                                const float* __restrict__ sh,
                                                void* __restrict__ OutA,
                                                f16* __restrict__ OutV) {
    constexpr int K  = (MODE == 2) ? 512 : 256;
    constexpr int KS = K / 32;                 // 8 or 16
    constexpr int MF = (MODE == 0) ? 2 : 1;    // 32-row or 16-row wave tile
    constexpr int BM = 64 * MF;                // 128 or 64 rows per block (4 waves)
    constexpr int NT = (MODE == 0) ? 640 : (MODE == 1 ? 128 : 384);
    constexpr int NC = NT / 64;

    const int t = threadIdx.x;
    const int lane = t & 63, wid = t >> 6;
    const int fr = lane & 15, kg = lane >> 4;
    const int m0 = blockIdx.x * BM;
    const int wrow0 = m0 + wid * (16 * MF);

    // ---- load A fragments into registers (A read exactly once) ----
    f16x8 af[MF][KS];
#pragma unroll
    for (int mf = 0; mf < MF; ++mf) {
        const int m = wrow0 + mf * 16 + fr;
        size_t arow;
        if constexpr (MODE == 1) {
            int b = m / 196, nn = m - b * 196;
            arow = (size_t)b * 784 + (nn / 14) * 56 + (nn % 14) * 2;
        } else {
            arow = (size_t)m;
        }
#pragma unroll
        for (int ks = 0; ks < KS; ++ks) {
            if constexpr (MODE == 2) {
                af[mf][ks] = *(const f16x8*)((const f16*)Ap + arow * K + ks * 32 + kg * 8);
            } else {
                const float* a = (const float*)Ap + arow * 256 + ks * 32 + kg * 8;
                fvec4 v0 = *(const fvec4*)a;
                fvec4 v1 = *(const fvec4*)(a + 4);
                f16x8 hv;
                hv[0] = (f16)v0[0]; hv[1] = (f16)v0[1]; hv[2] = (f16)v0[2]; hv[3] = (f16)v0[3];
                hv[4] = (f16)v1[0]; hv[5] = (f16)v1[1]; hv[6] = (f16)v1[2]; hv[7] = (f16)v1[3];
                af[mf][ks] = hv;
            }
        }
    }

    const int rg = kg * 4;
    for (int c = 0; c < NC; ++c) {
        f32x4 acc[MF][4];
#pragma unroll
        for (int i = 0; i < MF; ++i)
#pragma unroll
            for (int j = 0; j < 4; ++j) acc[i][j] = (f32x4){0.f, 0.f, 0.f, 0.f};

#pragma unroll
        for (int ks = 0; ks < KS; ++ks) {
            f16x8 bfr[4];
#pragma unroll
            for (int nf = 0; nf < 4; ++nf) {
                const int n = c * 64 + nf * 16 + fr;
                bfr[nf] = *(const f16x8*)(Wf + (size_t)n * K + ks * 32 + kg * 8);
            }
#pragma unroll
            for (int mf = 0; mf < MF; ++mf)
#pragma unroll
                for (int nf = 0; nf < 4; ++nf)
                    acc[mf][nf] = mfma16(af[mf][ks], bfr[nf], acc[mf][nf]);
        }

        // ---- epilogue ----
#pragma unroll
        for (int mf = 0; mf < MF; ++mf) {
            const int mbase = wrow0 + mf * 16 + rg;   // 4 consecutive output rows
#pragma unroll
            for (int nf = 0; nf < 4; ++nf) {
                const int n = c * 64 + nf * 16 + fr;
                const float scn = sc[n], shn = sh[n];
                if constexpr (MODE == 0) {
                    const int b = mbase / 784;
                    const int nn = mbase - b * 784;      // 4-row group stays in one b
                    const int hd = n / 80;
                    const int cc = n - hd * 80;
                    const size_t bh = (size_t)(b * 8 + hd);
                    if (cc < 16) {
#pragma unroll
                        for (int r = 0; r < 4; ++r) {
                            float y = acc[mf][nf][r] * scn + shn;
                            ((f16*)OutA)[(bh * NKEYP + nn + r) * 16 + cc] = (f16)y;
                        }
                    } else {
                        f16x4 pv;
#pragma unroll
                        for (int r = 0; r < 4; ++r) pv[r] = (f16)(acc[mf][nf][r] * scn + shn);
                        *(f16x4*)(OutV + (bh * 64 + (cc - 16)) * NKEYP + nn) = pv;
                    }
                } else if constexpr (MODE == 1) {
                    const int b = mbase / 196;
                    const int nn = mbase - b * 196;
                    const int hd = n >> 4, cc = n & 15;
                    const size_t bh = (size_t)(b * 8 + hd);
#pragma unroll
                    for (int r = 0; r < 4; ++r) {
                        float y = acc[mf][nf][r] * scn + shn;
                        ((f16*)OutA)[(bh * NQP + nn + r) * 16 + cc] = (f16)y;
                    }
                } else {
#pragma unroll
                    for (int r = 0; r < 4; ++r) {
                        float y = acc[mf][nf][r] * scn + shn;
                        ((float*)OutA)[(size_t)(mbase + r) * 384 + n] = y;
                    }
                }
            }
        }
    }
}

// ---------------- fused attention (unchanged from round 2) ----------------
__global__ __launch_bounds__(64) void attn_fused(const f16* __restrict__ kb,
                                                 const f16* __restrict__ vtb,
                                                 const f16* __restrict__ qw,
                                                 const f16* __restrict__ biasT,
                                                 f16* __restrict__ ao) {
    const int blk = blockIdx.x;
    const int qt = blk % 7;
    const int bh = blk / 7;
    const int b = bh >> 3, h = bh & 7;
    const int lane = threadIdx.x;
    const int l31 = lane & 31;
    const int hh = lane >> 5;
    const int q0 = qt * 32;

    const f16* kp = kb + (size_t)bh * (NKEYP * 16);
    const f16* vp = vtb + (size_t)bh * (64 * NKEYP) + (size_t)l31 * NKEYP;
    const f16x8 bq = *(const f16x8*)(qw + ((size_t)bh * NQP + q0 + l31) * 16 + hh * 8);
    const f16* bbq = biasT + ((size_t)h * NQP + (q0 + l31)) * NKEYP;

    float mrun = -1e30f;
    float lsum = 0.f;
    f32x16 o0 = z16(), o1 = z16();

    for (int key0 = 0; key0 < NKEY; key0 += 32) {
        f16x8 ak = *(const f16x8*)(kp + (size_t)(key0 + l31) * 16 + hh * 8);
        f32x16 s = mfma32(ak, bq, z16());
        const bool tail = (key0 + 32) > NKEY;
        f16x4 bw[4];
#pragma unroll
        for (int g = 0; g < 4; ++g)
            bw[g] = *(const f16x4*)(bbq + key0 + g * 8 + hh * 4);
        float p[16];
        float cmax = -3.0e38f;
#pragma unroll
        for (int r = 0; r < 16; ++r) {
            const int cr = (r & 3) + ((r >> 2) << 3) + (hh << 2);
            float sv = s[r] * 0.25f + (float)bw[r >> 2][r & 3];
            if (tail && (key0 + cr) >= NKEY) sv = -1e30f;
            p[r] = sv;
            cmax = fmaxf(cmax, sv);
        }
        cmax = fmaxf(cmax, __shfl_xor(cmax, 32));
        if (__any(cmax > mrun + 8.f)) {          // defer-max
            float mnew = fmaxf(mrun, cmax);
            float f = __expf(mrun - mnew);
            mrun = mnew;
            lsum *= f;
#pragma unroll
            for (int r = 0; r < 16; ++r) {
                const int cr = (r & 3) + ((r >> 2) << 3) + (hh << 2);
                float fr2 = __shfl(f, cr);
                o0[r] *= fr2;
                o1[r] *= fr2;
            }
        }
        float psum = 0.f;
#pragma unroll
        for (int r = 0; r < 16; ++r) {
            p[r] = __expf(p[r] - mrun);
            psum += p[r];
        }
        lsum += psum;
        unsigned g0l = pk2(p[0], p[1]),   g0h = pk2(p[2], p[3]);
        unsigned g1l = pk2(p[4], p[5]),   g1h = pk2(p[6], p[7]);
        unsigned g2l = pk2(p[8], p[9]),   g2h = pk2(p[10], p[11]);
        unsigned g3l = pk2(p[12], p[13]), g3h = pk2(p[14], p[15]);
        __builtin_amdgcn_s_setprio(1);
#pragma unroll
        for (int sH = 0; sH < 2; ++sH) {
            unsigned self_lo = sH ? (hh ? g3l : g2l) : (hh ? g1l : g0l);
            unsigned self_hi = sH ? (hh ? g3h : g2h) : (hh ? g1h : g0h);
            unsigned tx_lo   = sH ? (hh ? g2l : g3l) : (hh ? g0l : g1l);
            unsigned tx_hi   = sH ? (hh ? g2h : g3h) : (hh ? g0h : g1h);
            unsigned rx_lo = __shfl_xor(tx_lo, 32);
            unsigned rx_hi = __shfl_xor(tx_hi, 32);
            uint4v w;
            w[0] = hh ? rx_lo : self_lo;
            w[1] = hh ? rx_hi : self_hi;
            w[2] = hh ? self_lo : rx_lo;
            w[3] = hh ? self_hi : rx_hi;
            f16x8 pa = __builtin_bit_cast(f16x8, w);
            const f16* vrow = vp + key0 + sH * 16 + hh * 8;
            f16x8 bv0 = *(const f16x8*)(vrow);
            f16x8 bv1 = *(const f16x8*)(vrow + 32 * NKEYP);
            o0 = mfma32(pa, bv0, o0);
            o1 = mfma32(pa, bv1, o1);
        }
        __builtin_amdgcn_s_setprio(0);
    }
    lsum += __shfl_xor(lsum, 32);
    const float inv = 1.0f / lsum;
#pragma unroll
    for (int r = 0; r < 16; ++r) {
        const int cr = (r & 3) + ((r >> 2) << 3) + (hh << 2);
        const float iq = __shfl(inv, cr);
        const int qg = q0 + cr;
        if (qg < NQ) {
            float v0 = o0[r] * iq, v1 = o1[r] * iq;
            float h0 = v0 * fminf(fmaxf(v0 + 3.f, 0.f), 6.f) * (1.f / 6.f);
            float h1 = v1 * fminf(fmaxf(v1 + 3.f, 0.f), 6.f) * (1.f / 6.f);
            f16* dst = ao + ((size_t)b * NQ + qg) * 512 + h * 64 + l31;
            dst[0] = (f16)h0;
            dst[32] = (f16)h1;
        }
    }
}

// ---------------- launch ----------------
extern "C" void kernel_launch(void* const* d_in, const int* in_sizes, int n_in,
                              void* d_out, int out_size, void* d_ws, size_t ws_size,
                              hipStream_t stream) {
    (void)n_in; (void)out_size; (void)ws_size;
    const float* hidden = (const float*)d_in[0];
    const float* w_kv   = (const float*)d_in[1];
    const float* w_q    = (const float*)d_in[6];
    const float* w_p    = (const float*)d_in[11];
    const float* biases = (const float*)d_in[16];
    const int*   idxs   = (const int*)d_in[17];
    const int n_off = in_sizes[16] / 8;

    char* ws = (char*)d_ws;
    const size_t OFF_K  = 0;                       // 26,214,400
    const size_t OFF_V  = 26214400;                // 104,857,600
    const size_t OFF_Q  = 131072000;               //   7,340,032
    const size_t OFF_AO = 138412032;               //  25,690,112
    const size_t OFF_BT = 164102144;               //   2,867,200
    const size_t OFF_W  = 166969344;               //     786,432
    const size_t OFF_SC = 167755776;               //       9,216
    f16*   kbuf  = (f16*)(ws + OFF_K);
    f16*   vbuf  = (f16*)(ws + OFF_V);
    f16*   qbuf  = (f16*)(ws + OFF_Q);
    f16*   aobuf = (f16*)(ws + OFF_AO);
    f16*   btbuf = (f16*)(ws + OFF_BT);
    f16*   wf16  = (f16*)(ws + OFF_W);
    float* scbuf = (float*)(ws + OFF_SC);

    prep_scales_all<<<5, 256, 0, stream>>>(
        (const float*)d_in[2], (const float*)d_in[3], (const float*)d_in[4], (const float*)d_in[5],
        (const float*)d_in[7], (const float*)d_in[8], (const float*)d_in[9], (const float*)d_in[10],
        (const float*)d_in[12], (const float*)d_in[13], (const float*)d_in[14], (const float*)d_in[15],
        scbuf);
    conv_w<<<384, 256, 0, stream>>>(w_kv, w_q, w_p, wf16);
    prep_bias<<<5600, 256, 0, stream>>>(biases, idxs, btbuf, n_off);
    hipMemsetAsync(qbuf, 0, (size_t)1024 * NQP * 16 * 2, stream);  // zero q pad rows
    gemm_reg<0><<<784, 256, 0, stream>>>(hidden, wf16, scbuf, scbuf + 640, kbuf, vbuf);
    gemm_reg<1><<<392, 256, 0, stream>>>(hidden, wf16 + 163840, scbuf + 1280, scbuf + 1408, qbuf, nullptr);
    attn_fused<<<7168, 64, 0, stream>>>(kbuf, vbuf, qbuf, btbuf, aobuf);
    gemm_reg<2><<<392, 256, 0, stream>>>(aobuf, wf16 + 196608, scbuf + 1536, scbuf + 1920, d_out, nullptr);
}

// Round 4
// 459.861 us; speedup vs baseline: 1.0797x; 1.0797x over previous
//
#include <hip/hip_runtime.h>

typedef _Float16 f16;
typedef __attribute__((ext_vector_type(2))) _Float16 f16x2;
typedef __attribute__((ext_vector_type(4))) _Float16 f16x4;
typedef __attribute__((ext_vector_type(8))) _Float16 f16x8;
typedef __attribute__((ext_vector_type(4))) float fvec4;
typedef __attribute__((ext_vector_type(4))) float f32x4;
typedef __attribute__((ext_vector_type(16))) float f32x16;
typedef __attribute__((ext_vector_type(4))) unsigned int uint4v;

#define NKEY 784
#define NKEYP 800
#define NQ 196
#define NQP 224

static __device__ __forceinline__ f32x4 mfma16(f16x8 a, f16x8 b, f32x4 c) {
    return __builtin_amdgcn_mfma_f32_16x16x32_f16(a, b, c, 0, 0, 0);
}
static __device__ __forceinline__ f32x16 mfma32(f16x8 a, f16x8 b, f32x16 c) {
    return __builtin_amdgcn_mfma_f32_32x32x16_f16(a, b, c, 0, 0, 0);
}
static __device__ __forceinline__ unsigned pk2(float a, float b) {
    f16x2 t; t[0] = (_Float16)a; t[1] = (_Float16)b;
    return __builtin_bit_cast(unsigned, t);
}
static __device__ __forceinline__ f32x16 z16() {
    f32x16 v;
#pragma unroll
    for (int i = 0; i < 16; ++i) v[i] = 0.f;
    return v;
}

// ---------------- prep: fold BN into scale/shift (all three BNs) ----------------
__global__ void prep_scales_all(const float* __restrict__ kg, const float* __restrict__ kb,
                                const float* __restrict__ km, const float* __restrict__ kvv,
                                const float* __restrict__ qg, const float* __restrict__ qb,
                                const float* __restrict__ qm, const float* __restrict__ qv,
                                const float* __restrict__ pg, const float* __restrict__ pb,
                                const float* __restrict__ pm, const float* __restrict__ pv,
                                float* __restrict__ sb) {
    int i = blockIdx.x * 256 + threadIdx.x;
    if (i < 640) {
        float s = kg[i] * rsqrtf(kvv[i] + 1e-5f);
        sb[i] = s; sb[640 + i] = kb[i] - km[i] * s;
    } else if (i < 768) {
        int j = i - 640;
        float s = qg[j] * rsqrtf(qv[j] + 1e-5f);
        sb[1280 + j] = s; sb[1408 + j] = qb[j] - qm[j] * s;
    } else if (i < 1152) {
        int j = i - 768;
        float s = pg[j] * rsqrtf(pv[j] + 1e-5f);
        sb[1536 + j] = s; sb[1920 + j] = pb[j] - pm[j] * s;
    }
}

// ---------------- prep: convert weights to f16, k-major fragment layout ----------------
// Wt element (n, k) at [(k/8)*NT + n]*8 + (k%8)  (per weight matrix)
__global__ void conv_w(const float* __restrict__ wkv, const float* __restrict__ wq,
                       const float* __restrict__ wp, f16* __restrict__ out) {
    int i = blockIdx.x * 256 + threadIdx.x;   // 49152 threads = 20480 + 4096 + 24576
    const float* src;
    f16* dst;
    int kc, n, K;
    if (i < 20480)      { int j = i;         kc = j / 640, n = j - kc * 640; src = wkv; dst = out + (size_t)j * 8;            K = 256; }
    else if (i < 24576) { int j = i - 20480; kc = j / 128, n = j - kc * 128; src = wq;  dst = out + 163840 + (size_t)j * 8;   K = 256; }
    else                { int j = i - 24576; kc = j / 384, n = j - kc * 384; src = wp;  dst = out + 196608 + (size_t)j * 8;   K = 512; }
    const float* s = src + (size_t)n * K + kc * 8;
    fvec4 v0 = *(const fvec4*)s;
    fvec4 v1 = *(const fvec4*)(s + 4);
    f16x8 h;
    h[0] = (f16)v0[0]; h[1] = (f16)v0[1]; h[2] = (f16)v0[2]; h[3] = (f16)v0[3];
    h[4] = (f16)v1[0]; h[5] = (f16)v1[1]; h[6] = (f16)v1[2]; h[7] = (f16)v1[3];
    *(f16x8*)dst = h;
}

// ---------------- prep: gather bias f16 [h][q(224)][key(800)] ----------------
__global__ void prep_bias(const float* __restrict__ biases, const int* __restrict__ idxs,
                          f16* __restrict__ biasT, int n_off) {
    int tid = blockIdx.x * 256 + threadIdx.x;   // 8*224*800
    int h = tid / (NQP * NKEYP);
    int rem = tid - h * (NQP * NKEYP);
    int q = rem / NKEYP;
    int key = rem - q * NKEYP;
    float v = 0.f;
    if (q < NQ && key < NKEY) v = biases[h * n_off + idxs[q * NKEY + key]];
    biasT[tid] = (f16)v;
}

// ---------------- register-A GEMM, k-major W, BM=64, wave=16 rows ----------------
// MODE 0: kv  : A f32 [100352][256] -> K f16 [1024][800][16] + V^T f16 [1024][64][800]
// MODE 1: q   : A f32 subsampled   -> q f16 [1024][224][16]   (grid.y = 2 N-halves)
// MODE 2: proj: A f16 [25088][512] -> out f32 [25088][384]    (grid.y = 2 N-halves)
template <int MODE>
__global__ __launch_bounds__(256) void gemm_reg(const void* __restrict__ Ap,
                                                const f16* __restrict__ Wt,
                                                const float* __restrict__ sc,
                                                const float* __restrict__ sh,
                                                void* __restrict__ OutA,
                                                f16* __restrict__ OutV) {
    constexpr int K  = (MODE == 2) ? 512 : 256;
    constexpr int KS = K / 32;
    constexpr int NT = (MODE == 0) ? 640 : (MODE == 1 ? 128 : 384);
    constexpr int NCP = (MODE == 0) ? 10 : (MODE == 1 ? 1 : 3);   // chunks per block

    const int t = threadIdx.x;
    const int lane = t & 63, wid = t >> 6;
    const int fr = lane & 15, kg = lane >> 4;
    const int m0 = blockIdx.x * 64;
    const int nb0 = blockIdx.y * (NCP * 64);
    const int mrow = m0 + wid * 16 + fr;

    // ---- A fragments into registers (read once) ----
    size_t arow;
    if constexpr (MODE == 1) {
        int b = mrow / 196, nn = mrow - b * 196;
        arow = (size_t)b * 784 + (nn / 14) * 56 + (nn % 14) * 2;
    } else {
        arow = (size_t)mrow;
    }
    f16x8 af[KS];
#pragma unroll
    for (int ks = 0; ks < KS; ++ks) {
        if constexpr (MODE == 2) {
            af[ks] = *(const f16x8*)((const f16*)Ap + arow * K + ks * 32 + kg * 8);
        } else {
            const float* a = (const float*)Ap + arow * 256 + ks * 32 + kg * 8;
            fvec4 v0 = *(const fvec4*)a;
            fvec4 v1 = *(const fvec4*)(a + 4);
            f16x8 hv;
            hv[0] = (f16)v0[0]; hv[1] = (f16)v0[1]; hv[2] = (f16)v0[2]; hv[3] = (f16)v0[3];
            hv[4] = (f16)v1[0]; hv[5] = (f16)v1[1]; hv[6] = (f16)v1[2]; hv[7] = (f16)v1[3];
            af[ks] = hv;
        }
    }

    const int rg = kg * 4;
    for (int c = 0; c < NCP; ++c) {
        const int n0c = nb0 + c * 64;
        f32x4 acc[4];
#pragma unroll
        for (int j = 0; j < 4; ++j) acc[j] = (f32x4){0.f, 0.f, 0.f, 0.f};

#pragma unroll
        for (int ks = 0; ks < KS; ++ks) {
            f16x8 bfr[4];
#pragma unroll
            for (int nf = 0; nf < 4; ++nf)
                bfr[nf] = *(const f16x8*)(Wt + ((size_t)(ks * 4 + kg) * NT + n0c + nf * 16 + fr) * 8);
#pragma unroll
            for (int nf = 0; nf < 4; ++nf)
                acc[nf] = mfma16(af[ks], bfr[nf], acc[nf]);
        }

        // ---- epilogue ----
        const int mbase = m0 + wid * 16 + rg;   // 4 consecutive output rows
#pragma unroll
        for (int nf = 0; nf < 4; ++nf) {
            const int n = n0c + nf * 16 + fr;
            const float scn = sc[n], shn = sh[n];
            if constexpr (MODE == 0) {
                const int b = mbase / 784;
                const int nn = mbase - b * 784;      // %4==0, 4-row group in one b
                const int hd = n / 80;
                const int cc = n - hd * 80;
                const size_t bh = (size_t)(b * 8 + hd);
                if (cc < 16) {
#pragma unroll
                    for (int r = 0; r < 4; ++r) {
                        float y = acc[nf][r] * scn + shn;
                        ((f16*)OutA)[(bh * NKEYP + nn + r) * 16 + cc] = (f16)y;
                    }
                } else {
                    f16x4 pv;
#pragma unroll
                    for (int r = 0; r < 4; ++r) pv[r] = (f16)(acc[nf][r] * scn + shn);
                    *(f16x4*)(OutV + (bh * 64 + (cc - 16)) * NKEYP + nn) = pv;
                }
            } else if constexpr (MODE == 1) {
                const int b = mbase / 196;
                const int nn = mbase - b * 196;
                const int hd = n >> 4, cc = n & 15;
                const size_t bh = (size_t)(b * 8 + hd);
#pragma unroll
                for (int r = 0; r < 4; ++r) {
                    float y = acc[nf][r] * scn + shn;
                    ((f16*)OutA)[(bh * NQP + nn + r) * 16 + cc] = (f16)y;
                }
            } else {
#pragma unroll
                for (int r = 0; r < 4; ++r) {
                    float y = acc[nf][r] * scn + shn;
                    ((float*)OutA)[(size_t)(mbase + r) * 384 + n] = y;
                }
            }
        }
    }
}

// ---------------- fused attention (unchanged) ----------------
__global__ __launch_bounds__(64) void attn_fused(const f16* __restrict__ kb,
                                                 const f16* __restrict__ vtb,
                                                 const f16* __restrict__ qw,
                                                 const f16* __restrict__ biasT,
                                                 f16* __restrict__ ao) {
    const int blk = blockIdx.x;
    const int qt = blk % 7;
    const int bh = blk / 7;
    const int b = bh >> 3, h = bh & 7;
    const int lane = threadIdx.x;
    const int l31 = lane & 31;
    const int hh = lane >> 5;
    const int q0 = qt * 32;

    const f16* kp = kb + (size_t)bh * (NKEYP * 16);
    const f16* vp = vtb + (size_t)bh * (64 * NKEYP) + (size_t)l31 * NKEYP;
    const f16x8 bq = *(const f16x8*)(qw + ((size_t)bh * NQP + q0 + l31) * 16 + hh * 8);
    const f16* bbq = biasT + ((size_t)h * NQP + (q0 + l31)) * NKEYP;

    float mrun = -1e30f;
    float lsum = 0.f;
    f32x16 o0 = z16(), o1 = z16();

    for (int key0 = 0; key0 < NKEY; key0 += 32) {
        f16x8 ak = *(const f16x8*)(kp + (size_t)(key0 + l31) * 16 + hh * 8);
        f32x16 s = mfma32(ak, bq, z16());
        const bool tail = (key0 + 32) > NKEY;
        f16x4 bw[4];
#pragma unroll
        for (int g = 0; g < 4; ++g)
            bw[g] = *(const f16x4*)(bbq + key0 + g * 8 + hh * 4);
        float p[16];
        float cmax = -3.0e38f;
#pragma unroll
        for (int r = 0; r < 16; ++r) {
            const int cr = (r & 3) + ((r >> 2) << 3) + (hh << 2);
            float sv = s[r] * 0.25f + (float)bw[r >> 2][r & 3];
            if (tail && (key0 + cr) >= NKEY) sv = -1e30f;
            p[r] = sv;
            cmax = fmaxf(cmax, sv);
        }
        cmax = fmaxf(cmax, __shfl_xor(cmax, 32));
        if (__any(cmax > mrun + 8.f)) {          // defer-max
            float mnew = fmaxf(mrun, cmax);
            float f = __expf(mrun - mnew);
            mrun = mnew;
            lsum *= f;
#pragma unroll
            for (int r = 0; r < 16; ++r) {
                const int cr = (r & 3) + ((r >> 2) << 3) + (hh << 2);
                float fr2 = __shfl(f, cr);
                o0[r] *= fr2;
                o1[r] *= fr2;
            }
        }
        float psum = 0.f;
#pragma unroll
        for (int r = 0; r < 16; ++r) {
            p[r] = __expf(p[r] - mrun);
            psum += p[r];
        }
        lsum += psum;
        unsigned g0l = pk2(p[0], p[1]),   g0h = pk2(p[2], p[3]);
        unsigned g1l = pk2(p[4], p[5]),   g1h = pk2(p[6], p[7]);
        unsigned g2l = pk2(p[8], p[9]),   g2h = pk2(p[10], p[11]);
        unsigned g3l = pk2(p[12], p[13]), g3h = pk2(p[14], p[15]);
        __builtin_amdgcn_s_setprio(1);
#pragma unroll
        for (int sH = 0; sH < 2; ++sH) {
            unsigned self_lo = sH ? (hh ? g3l : g2l) : (hh ? g1l : g0l);
            unsigned self_hi = sH ? (hh ? g3h : g2h) : (hh ? g1h : g0h);
            unsigned tx_lo   = sH ? (hh ? g2l : g3l) : (hh ? g0l : g1l);
            unsigned tx_hi   = sH ? (hh ? g2h : g3h) : (hh ? g0h : g1h);
            unsigned rx_lo = __shfl_xor(tx_lo, 32);
            unsigned rx_hi = __shfl_xor(tx_hi, 32);
            uint4v w;
            w[0] = hh ? rx_lo : self_lo;
            w[1] = hh ? rx_hi : self_hi;
            w[2] = hh ? self_lo : rx_lo;
            w[3] = hh ? self_hi : rx_hi;
            f16x8 pa = __builtin_bit_cast(f16x8, w);
            const f16* vrow = vp + key0 + sH * 16 + hh * 8;
            f16x8 bv0 = *(const f16x8*)(vrow);
            f16x8 bv1 = *(const f16x8*)(vrow + 32 * NKEYP);
            o0 = mfma32(pa, bv0, o0);
            o1 = mfma32(pa, bv1, o1);
        }
        __builtin_amdgcn_s_setprio(0);
    }
    lsum += __shfl_xor(lsum, 32);
    const float inv = 1.0f / lsum;
#pragma unroll
    for (int r = 0; r < 16; ++r) {
        const int cr = (r & 3) + ((r >> 2) << 3) + (hh << 2);
        const float iq = __shfl(inv, cr);
        const int qg = q0 + cr;
        if (qg < NQ) {
            float v0 = o0[r] * iq, v1 = o1[r] * iq;
            float h0 = v0 * fminf(fmaxf(v0 + 3.f, 0.f), 6.f) * (1.f / 6.f);
            float h1 = v1 * fminf(fmaxf(v1 + 3.f, 0.f), 6.f) * (1.f / 6.f);
            f16* dst = ao + ((size_t)b * NQ + qg) * 512 + h * 64 + l31;
            dst[0] = (f16)h0;
            dst[32] = (f16)h1;
        }
    }
}

// ---------------- launch ----------------
extern "C" void kernel_launch(void* const* d_in, const int* in_sizes, int n_in,
                              void* d_out, int out_size, void* d_ws, size_t ws_size,
                              hipStream_t stream) {
    (void)n_in; (void)out_size; (void)ws_size;
    const float* hidden = (const float*)d_in[0];
    const float* w_kv   = (const float*)d_in[1];
    const float* w_q    = (const float*)d_in[6];
    const float* w_p    = (const float*)d_in[11];
    const float* biases = (const float*)d_in[16];
    const int*   idxs   = (const int*)d_in[17];
    const int n_off = in_sizes[16] / 8;

    char* ws = (char*)d_ws;
    const size_t OFF_K  = 0;                       // 26,214,400
    const size_t OFF_V  = 26214400;                // 104,857,600
    const size_t OFF_Q  = 131072000;               //   7,340,032
    const size_t OFF_AO = 138412032;               //  25,690,112
    const size_t OFF_BT = 164102144;               //   2,867,200
    const size_t OFF_W  = 166969344;               //     786,432
    const size_t OFF_SC = 167755776;               //       9,216
    f16*   kbuf  = (f16*)(ws + OFF_K);
    f16*   vbuf  = (f16*)(ws + OFF_V);
    f16*   qbuf  = (f16*)(ws + OFF_Q);
    f16*   aobuf = (f16*)(ws + OFF_AO);
    f16*   btbuf = (f16*)(ws + OFF_BT);
    f16*   wf16  = (f16*)(ws + OFF_W);
    float* scbuf = (float*)(ws + OFF_SC);

    prep_scales_all<<<5, 256, 0, stream>>>(
        (const float*)d_in[2], (const float*)d_in[3], (const float*)d_in[4], (const float*)d_in[5],
        (const float*)d_in[7], (const float*)d_in[8], (const float*)d_in[9], (const float*)d_in[10],
        (const float*)d_in[12], (const float*)d_in[13], (const float*)d_in[14], (const float*)d_in[15],
        scbuf);
    conv_w<<<192, 256, 0, stream>>>(w_kv, w_q, w_p, wf16);
    prep_bias<<<5600, 256, 0, stream>>>(biases, idxs, btbuf, n_off);
    hipMemsetAsync(qbuf, 0, (size_t)1024 * NQP * 16 * 2, stream);  // zero q pad rows
    gemm_reg<0><<<dim3(1568, 1), 256, 0, stream>>>(hidden, wf16, scbuf, scbuf + 640, kbuf, vbuf);
    gemm_reg<1><<<dim3(392, 2), 256, 0, stream>>>(hidden, wf16 + 163840, scbuf + 1280, scbuf + 1408, qbuf, nullptr);
    attn_fused<<<7168, 64, 0, stream>>>(kbuf, vbuf, qbuf, btbuf, aobuf);
    gemm_reg<2><<<dim3(392, 2), 256, 0, stream>>>(aobuf, wf16 + 196608, scbuf + 1536, scbuf + 1920, d_out, nullptr);
}

// Round 5
// 376.794 us; speedup vs baseline: 1.3177x; 1.2205x over previous
//
#include <hip/hip_runtime.h>

typedef _Float16 f16;
typedef __attribute__((ext_vector_type(2))) _Float16 f16x2;
typedef __attribute__((ext_vector_type(4))) _Float16 f16x4;
typedef __attribute__((ext_vector_type(8))) _Float16 f16x8;
typedef __attribute__((ext_vector_type(4))) float fvec4;
typedef __attribute__((ext_vector_type(4))) float f32x4;
typedef __attribute__((ext_vector_type(16))) float f32x16;
typedef __attribute__((ext_vector_type(4))) unsigned int uint4v;

#define NKEY 784
#define NKEYP 800
#define NQ 196
#define NQP 224

static __device__ __forceinline__ f32x4 mfma16(f16x8 a, f16x8 b, f32x4 c) {
    return __builtin_amdgcn_mfma_f32_16x16x32_f16(a, b, c, 0, 0, 0);
}
static __device__ __forceinline__ f32x16 mfma32(f16x8 a, f16x8 b, f32x16 c) {
    return __builtin_amdgcn_mfma_f32_32x32x16_f16(a, b, c, 0, 0, 0);
}
static __device__ __forceinline__ unsigned pk2(float a, float b) {
    f16x2 t; t[0] = (_Float16)a; t[1] = (_Float16)b;
    return __builtin_bit_cast(unsigned, t);
}
static __device__ __forceinline__ f32x16 z16() {
    f32x16 v;
#pragma unroll
    for (int i = 0; i < 16; ++i) v[i] = 0.f;
    return v;
}

// ---------------- prep: fold BN into scale/shift (all three BNs) ----------------
__global__ void prep_scales_all(const float* __restrict__ kg, const float* __restrict__ kb,
                                const float* __restrict__ km, const float* __restrict__ kvv,
                                const float* __restrict__ qg, const float* __restrict__ qb,
                                const float* __restrict__ qm, const float* __restrict__ qv,
                                const float* __restrict__ pg, const float* __restrict__ pb,
                                const float* __restrict__ pm, const float* __restrict__ pv,
                                float* __restrict__ sb) {
    int i = blockIdx.x * 256 + threadIdx.x;
    if (i < 640) {
        float s = kg[i] * rsqrtf(kvv[i] + 1e-5f);
        sb[i] = s; sb[640 + i] = kb[i] - km[i] * s;
    } else if (i < 768) {
        int j = i - 640;
        float s = qg[j] * rsqrtf(qv[j] + 1e-5f);
        sb[1280 + j] = s; sb[1408 + j] = qb[j] - qm[j] * s;
    } else if (i < 1152) {
        int j = i - 768;
        float s = pg[j] * rsqrtf(pv[j] + 1e-5f);
        sb[1536 + j] = s; sb[1920 + j] = pb[j] - pm[j] * s;
    }
}

// ---------------- prep: convert weights to f16, k-major fragment layout ----------------
// Wt element (n, k) at [(k/8)*NT + n]*8 + (k%8)  (per weight matrix)
__global__ void conv_w(const float* __restrict__ wkv, const float* __restrict__ wq,
                       const float* __restrict__ wp, f16* __restrict__ out) {
    int i = blockIdx.x * 256 + threadIdx.x;   // 49152 threads = 20480 + 4096 + 24576
    const float* src;
    f16* dst;
    int kc, n, K;
    if (i < 20480)      { int j = i;         kc = j / 640, n = j - kc * 640; src = wkv; dst = out + (size_t)j * 8;            K = 256; }
    else if (i < 24576) { int j = i - 20480; kc = j / 128, n = j - kc * 128; src = wq;  dst = out + 163840 + (size_t)j * 8;   K = 256; }
    else                { int j = i - 24576; kc = j / 384, n = j - kc * 384; src = wp;  dst = out + 196608 + (size_t)j * 8;   K = 512; }
    const float* s = src + (size_t)n * K + kc * 8;
    fvec4 v0 = *(const fvec4*)s;
    fvec4 v1 = *(const fvec4*)(s + 4);
    f16x8 h;
    h[0] = (f16)v0[0]; h[1] = (f16)v0[1]; h[2] = (f16)v0[2]; h[3] = (f16)v0[3];
    h[4] = (f16)v1[0]; h[5] = (f16)v1[1]; h[6] = (f16)v1[2]; h[7] = (f16)v1[3];
    *(f16x8*)dst = h;
}

// ---------------- prep: gather bias f16 [h][q(224)][key(800)] ----------------
__global__ void prep_bias(const float* __restrict__ biases, const int* __restrict__ idxs,
                          f16* __restrict__ biasT, int n_off) {
    int tid = blockIdx.x * 256 + threadIdx.x;   // 8*224*800
    int h = tid / (NQP * NKEYP);
    int rem = tid - h * (NQP * NKEYP);
    int q = rem / NKEYP;
    int key = rem - q * NKEYP;
    float v = 0.f;
    if (q < NQ && key < NKEY) v = biases[h * n_off + idxs[q * NKEY + key]];
    biasT[tid] = (f16)v;
}

// ---------------- register-A GEMM, k-major W, BM=64, wave=16 rows ----------------
// MODE 0: kv  : A f32 [100352][256] -> K f16 [1024][800][16] + V^T f16 [1024][64][800]
// MODE 1: q   : A f32 subsampled   -> q f16 [1024][224][16]   (grid.y = 2 N-halves)
// MODE 2: proj: A f16 [25088][512] -> out f32 [25088][384]    (grid.y = 2 N-halves)
template <int MODE>
__global__ __launch_bounds__(256) void gemm_reg(const void* __restrict__ Ap,
                                                const f16* __restrict__ Wt,
                                                const float* __restrict__ sc,
                                                const float* __restrict__ sh,
                                                void* __restrict__ OutA,
                                                f16* __restrict__ OutV) {
    constexpr int K  = (MODE == 2) ? 512 : 256;
    constexpr int KS = K / 32;
    constexpr int NT = (MODE == 0) ? 640 : (MODE == 1 ? 128 : 384);
    constexpr int NCP = (MODE == 0) ? 10 : (MODE == 1 ? 1 : 3);   // chunks per block

    const int t = threadIdx.x;
    const int lane = t & 63, wid = t >> 6;
    const int fr = lane & 15, kg = lane >> 4;
    const int m0 = blockIdx.x * 64;
    const int nb0 = blockIdx.y * (NCP * 64);
    const int mrow = m0 + wid * 16 + fr;

    // ---- A fragments into registers (read once) ----
    size_t arow;
    if constexpr (MODE == 1) {
        int b = mrow / 196, nn = mrow - b * 196;
        arow = (size_t)b * 784 + (nn / 14) * 56 + (nn % 14) * 2;
    } else {
        arow = (size_t)mrow;
    }
    f16x8 af[KS];
#pragma unroll
    for (int ks = 0; ks < KS; ++ks) {
        if constexpr (MODE == 2) {
            af[ks] = *(const f16x8*)((const f16*)Ap + arow * K + ks * 32 + kg * 8);
        } else {
            const float* a = (const float*)Ap + arow * 256 + ks * 32 + kg * 8;
            fvec4 v0 = *(const fvec4*)a;
            fvec4 v1 = *(const fvec4*)(a + 4);
            f16x8 hv;
            hv[0] = (f16)v0[0]; hv[1] = (f16)v0[1]; hv[2] = (f16)v0[2]; hv[3] = (f16)v0[3];
            hv[4] = (f16)v1[0]; hv[5] = (f16)v1[1]; hv[6] = (f16)v1[2]; hv[7] = (f16)v1[3];
            af[ks] = hv;
        }
    }

    const int rg = kg * 4;
    for (int c = 0; c < NCP; ++c) {
        const int n0c = nb0 + c * 64;
        f32x4 acc[4];
#pragma unroll
        for (int j = 0; j < 4; ++j) acc[j] = (f32x4){0.f, 0.f, 0.f, 0.f};

#pragma unroll
        for (int ks = 0; ks < KS; ++ks) {
            f16x8 bfr[4];
#pragma unroll
            for (int nf = 0; nf < 4; ++nf)
                bfr[nf] = *(const f16x8*)(Wt + ((size_t)(ks * 4 + kg) * NT + n0c + nf * 16 + fr) * 8);
#pragma unroll
            for (int nf = 0; nf < 4; ++nf)
                acc[nf] = mfma16(af[ks], bfr[nf], acc[nf]);
        }

        // ---- epilogue ----
        const int mbase = m0 + wid * 16 + rg;   // 4 consecutive output rows
#pragma unroll
        for (int nf = 0; nf < 4; ++nf) {
            const int n = n0c + nf * 16 + fr;
            const float scn = sc[n], shn = sh[n];
            if constexpr (MODE == 0) {
                const int b = mbase / 784;
                const int nn = mbase - b * 784;      // %4==0, 4-row group in one b
                const int hd = n / 80;
                const int cc = n - hd * 80;
                const size_t bh = (size_t)(b * 8 + hd);
                if (cc < 16) {
#pragma unroll
                    for (int r = 0; r < 4; ++r) {
                        float y = acc[nf][r] * scn + shn;
                        ((f16*)OutA)[(bh * NKEYP + nn + r) * 16 + cc] = (f16)y;
                    }
                } else {
                    f16x4 pv;
#pragma unroll
                    for (int r = 0; r < 4; ++r) pv[r] = (f16)(acc[nf][r] * scn + shn);
                    *(f16x4*)(OutV + (bh * 64 + (cc - 16)) * NKEYP + nn) = pv;
                }
            } else if constexpr (MODE == 1) {
                const int b = mbase / 196;
                const int nn = mbase - b * 196;
                const int hd = n >> 4, cc = n & 15;
                const size_t bh = (size_t)(b * 8 + hd);
#pragma unroll
                for (int r = 0; r < 4; ++r) {
                    float y = acc[nf][r] * scn + shn;
                    ((f16*)OutA)[(bh * NQP + nn + r) * 16 + cc] = (f16)y;
                }
            } else {
#pragma unroll
                for (int r = 0; r < 4; ++r) {
                    float y = acc[nf][r] * scn + shn;
                    ((float*)OutA)[(size_t)(mbase + r) * 384 + n] = y;
                }
            }
        }
    }
}

// ---------------- fused attention: block = (b,h), 7 waves = 7 q-tiles ----------------
// All 7 waves stream the SAME K/V slice (128 KB) -> compulsory HBM traffic only,
// re-reads served by L1/L2. Wave w owns q rows [32w, 32w+32).
__global__ __launch_bounds__(448) void attn_fused(const f16* __restrict__ kb,
                                                  const f16* __restrict__ vtb,
                                                  const f16* __restrict__ qw,
                                                  const f16* __restrict__ biasT,
                                                  f16* __restrict__ ao) {
    const int bh = blockIdx.x;
    const int b = bh >> 3, h = bh & 7;
    const int wid = threadIdx.x >> 6;      // q-tile 0..6
    const int lane = threadIdx.x & 63;
    const int l31 = lane & 31;
    const int hh = lane >> 5;
    const int q0 = wid * 32;

    const f16* kp = kb + (size_t)bh * (NKEYP * 16);
    const f16* vp = vtb + (size_t)bh * (64 * NKEYP) + (size_t)l31 * NKEYP;
    const f16x8 bq = *(const f16x8*)(qw + ((size_t)bh * NQP + q0 + l31) * 16 + hh * 8);
    const f16* bbq = biasT + ((size_t)h * NQP + (q0 + l31)) * NKEYP;

    float mrun = -1e30f;
    float lsum = 0.f;
    f32x16 o0 = z16(), o1 = z16();

    for (int key0 = 0; key0 < NKEY; key0 += 32) {
        f16x8 ak = *(const f16x8*)(kp + (size_t)(key0 + l31) * 16 + hh * 8);
        f32x16 s = mfma32(ak, bq, z16());
        const bool tail = (key0 + 32) > NKEY;
        f16x4 bw[4];
#pragma unroll
        for (int g = 0; g < 4; ++g)
            bw[g] = *(const f16x4*)(bbq + key0 + g * 8 + hh * 4);
        float p[16];
        float cmax = -3.0e38f;
#pragma unroll
        for (int r = 0; r < 16; ++r) {
            const int cr = (r & 3) + ((r >> 2) << 3) + (hh << 2);
            float sv = s[r] * 0.25f + (float)bw[r >> 2][r & 3];
            if (tail && (key0 + cr) >= NKEY) sv = -1e30f;
            p[r] = sv;
            cmax = fmaxf(cmax, sv);
        }
        cmax = fmaxf(cmax, __shfl_xor(cmax, 32));
        if (__any(cmax > mrun + 8.f)) {          // defer-max
            float mnew = fmaxf(mrun, cmax);
            float f = __expf(mrun - mnew);
            mrun = mnew;
            lsum *= f;
#pragma unroll
            for (int r = 0; r < 16; ++r) {
                const int cr = (r & 3) + ((r >> 2) << 3) + (hh << 2);
                float fr2 = __shfl(f, cr);
                o0[r] *= fr2;
                o1[r] *= fr2;
            }
        }
        float psum = 0.f;
#pragma unroll
        for (int r = 0; r < 16; ++r) {
            p[r] = __expf(p[r] - mrun);
            psum += p[r];
        }
        lsum += psum;
        unsigned g0l = pk2(p[0], p[1]),   g0h = pk2(p[2], p[3]);
        unsigned g1l = pk2(p[4], p[5]),   g1h = pk2(p[6], p[7]);
        unsigned g2l = pk2(p[8], p[9]),   g2h = pk2(p[10], p[11]);
        unsigned g3l = pk2(p[12], p[13]), g3h = pk2(p[14], p[15]);
        __builtin_amdgcn_s_setprio(1);
#pragma unroll
        for (int sH = 0; sH < 2; ++sH) {
            unsigned self_lo = sH ? (hh ? g3l : g2l) : (hh ? g1l : g0l);
            unsigned self_hi = sH ? (hh ? g3h : g2h) : (hh ? g1h : g0h);
            unsigned tx_lo   = sH ? (hh ? g2l : g3l) : (hh ? g0l : g1l);
            unsigned tx_hi   = sH ? (hh ? g2h : g3h) : (hh ? g0h : g1h);
            unsigned rx_lo = __shfl_xor(tx_lo, 32);
            unsigned rx_hi = __shfl_xor(tx_hi, 32);
            uint4v w;
            w[0] = hh ? rx_lo : self_lo;
            w[1] = hh ? rx_hi : self_hi;
            w[2] = hh ? self_lo : rx_lo;
            w[3] = hh ? self_hi : rx_hi;
            f16x8 pa = __builtin_bit_cast(f16x8, w);
            const f16* vrow = vp + key0 + sH * 16 + hh * 8;
            f16x8 bv0 = *(const f16x8*)(vrow);
            f16x8 bv1 = *(const f16x8*)(vrow + 32 * NKEYP);
            o0 = mfma32(pa, bv0, o0);
            o1 = mfma32(pa, bv1, o1);
        }
        __builtin_amdgcn_s_setprio(0);
    }
    lsum += __shfl_xor(lsum, 32);
    const float inv = 1.0f / lsum;
#pragma unroll
    for (int r = 0; r < 16; ++r) {
        const int cr = (r & 3) + ((r >> 2) << 3) + (hh << 2);
        const float iq = __shfl(inv, cr);
        const int qg = q0 + cr;
        if (qg < NQ) {
            float v0 = o0[r] * iq, v1 = o1[r] * iq;
            float h0 = v0 * fminf(fmaxf(v0 + 3.f, 0.f), 6.f) * (1.f / 6.f);
            float h1 = v1 * fminf(fmaxf(v1 + 3.f, 0.f), 6.f) * (1.f / 6.f);
            f16* dst = ao + ((size_t)b * NQ + qg) * 512 + h * 64 + l31;
            dst[0] = (f16)h0;
            dst[32] = (f16)h1;
        }
    }
}

// ---------------- launch ----------------
extern "C" void kernel_launch(void* const* d_in, const int* in_sizes, int n_in,
                              void* d_out, int out_size, void* d_ws, size_t ws_size,
                              hipStream_t stream) {
    (void)n_in; (void)out_size; (void)ws_size;
    const float* hidden = (const float*)d_in[0];
    const float* w_kv   = (const float*)d_in[1];
    const float* w_q    = (const float*)d_in[6];
    const float* w_p    = (const float*)d_in[11];
    const float* biases = (const float*)d_in[16];
    const int*   idxs   = (const int*)d_in[17];
    const int n_off = in_sizes[16] / 8;

    char* ws = (char*)d_ws;
    const size_t OFF_K  = 0;                       // 26,214,400
    const size_t OFF_V  = 26214400;                // 104,857,600
    const size_t OFF_Q  = 131072000;               //   7,340,032
    const size_t OFF_AO = 138412032;               //  25,690,112
    const size_t OFF_BT = 164102144;               //   2,867,200
    const size_t OFF_W  = 166969344;               //     786,432
    const size_t OFF_SC = 167755776;               //       9,216
    f16*   kbuf  = (f16*)(ws + OFF_K);
    f16*   vbuf  = (f16*)(ws + OFF_V);
    f16*   qbuf  = (f16*)(ws + OFF_Q);
    f16*   aobuf = (f16*)(ws + OFF_AO);
    f16*   btbuf = (f16*)(ws + OFF_BT);
    f16*   wf16  = (f16*)(ws + OFF_W);
    float* scbuf = (float*)(ws + OFF_SC);

    prep_scales_all<<<5, 256, 0, stream>>>(
        (const float*)d_in[2], (const float*)d_in[3], (const float*)d_in[4], (const float*)d_in[5],
        (const float*)d_in[7], (const float*)d_in[8], (const float*)d_in[9], (const float*)d_in[10],
        (const float*)d_in[12], (const float*)d_in[13], (const float*)d_in[14], (const float*)d_in[15],
        scbuf);
    conv_w<<<192, 256, 0, stream>>>(w_kv, w_q, w_p, wf16);
    prep_bias<<<5600, 256, 0, stream>>>(biases, idxs, btbuf, n_off);
    hipMemsetAsync(qbuf, 0, (size_t)1024 * NQP * 16 * 2, stream);  // zero q pad rows
    gemm_reg<0><<<dim3(1568, 1), 256, 0, stream>>>(hidden, wf16, scbuf, scbuf + 640, kbuf, vbuf);
    gemm_reg<1><<<dim3(392, 2), 256, 0, stream>>>(hidden, wf16 + 163840, scbuf + 1280, scbuf + 1408, qbuf, nullptr);
    attn_fused<<<1024, 448, 0, stream>>>(kbuf, vbuf, qbuf, btbuf, aobuf);
    gemm_reg<2><<<dim3(392, 2), 256, 0, stream>>>(aobuf, wf16 + 196608, scbuf + 1536, scbuf + 1920, d_out, nullptr);
}

// Round 6
// 372.051 us; speedup vs baseline: 1.3345x; 1.0127x over previous
//
#include <hip/hip_runtime.h>

typedef _Float16 f16;
typedef __attribute__((ext_vector_type(2))) _Float16 f16x2;
typedef __attribute__((ext_vector_type(4))) _Float16 f16x4;
typedef __attribute__((ext_vector_type(8))) _Float16 f16x8;
typedef __attribute__((ext_vector_type(4))) float fvec4;
typedef __attribute__((ext_vector_type(4))) float f32x4;
typedef __attribute__((ext_vector_type(16))) float f32x16;
typedef __attribute__((ext_vector_type(4))) unsigned int uint4v;

#define NKEY 784
#define NKEYP 800
#define NQ 196
#define NQP 224

static __device__ __forceinline__ f32x4 mfma16(f16x8 a, f16x8 b, f32x4 c) {
    return __builtin_amdgcn_mfma_f32_16x16x32_f16(a, b, c, 0, 0, 0);
}
static __device__ __forceinline__ f32x16 mfma32(f16x8 a, f16x8 b, f32x16 c) {
    return __builtin_amdgcn_mfma_f32_32x32x16_f16(a, b, c, 0, 0, 0);
}
static __device__ __forceinline__ unsigned pk2(float a, float b) {
    f16x2 t; t[0] = (_Float16)a; t[1] = (_Float16)b;
    return __builtin_bit_cast(unsigned, t);
}
static __device__ __forceinline__ f32x16 z16() {
    f32x16 v;
#pragma unroll
    for (int i = 0; i < 16; ++i) v[i] = 0.f;
    return v;
}

// ---------------- prep: fold BN into scale/shift (all three BNs) ----------------
__global__ void prep_scales_all(const float* __restrict__ kg, const float* __restrict__ kb,
                                const float* __restrict__ km, const float* __restrict__ kvv,
                                const float* __restrict__ qg, const float* __restrict__ qb,
                                const float* __restrict__ qm, const float* __restrict__ qv,
                                const float* __restrict__ pg, const float* __restrict__ pb,
                                const float* __restrict__ pm, const float* __restrict__ pv,
                                float* __restrict__ sb) {
    int i = blockIdx.x * 256 + threadIdx.x;
    if (i < 640) {
        float s = kg[i] * rsqrtf(kvv[i] + 1e-5f);
        sb[i] = s; sb[640 + i] = kb[i] - km[i] * s;
    } else if (i < 768) {
        int j = i - 640;
        float s = qg[j] * rsqrtf(qv[j] + 1e-5f);
        sb[1280 + j] = s; sb[1408 + j] = qb[j] - qm[j] * s;
    } else if (i < 1152) {
        int j = i - 768;
        float s = pg[j] * rsqrtf(pv[j] + 1e-5f);
        sb[1536 + j] = s; sb[1920 + j] = pb[j] - pm[j] * s;
    }
}

// ---------------- prep: convert weights to f16, k-major fragment layout ----------------
// Wt element (n, k) at [(k/8)*NT + n]*8 + (k%8)  (per weight matrix)
__global__ void conv_w(const float* __restrict__ wkv, const float* __restrict__ wq,
                       const float* __restrict__ wp, f16* __restrict__ out) {
    int i = blockIdx.x * 256 + threadIdx.x;   // 49152 threads = 20480 + 4096 + 24576
    const float* src;
    f16* dst;
    int kc, n, K;
    if (i < 20480)      { int j = i;         kc = j / 640, n = j - kc * 640; src = wkv; dst = out + (size_t)j * 8;            K = 256; }
    else if (i < 24576) { int j = i - 20480; kc = j / 128, n = j - kc * 128; src = wq;  dst = out + 163840 + (size_t)j * 8;   K = 256; }
    else                { int j = i - 24576; kc = j / 384, n = j - kc * 384; src = wp;  dst = out + 196608 + (size_t)j * 8;   K = 512; }
    const float* s = src + (size_t)n * K + kc * 8;
    fvec4 v0 = *(const fvec4*)s;
    fvec4 v1 = *(const fvec4*)(s + 4);
    f16x8 h;
    h[0] = (f16)v0[0]; h[1] = (f16)v0[1]; h[2] = (f16)v0[2]; h[3] = (f16)v0[3];
    h[4] = (f16)v1[0]; h[5] = (f16)v1[1]; h[6] = (f16)v1[2]; h[7] = (f16)v1[3];
    *(f16x8*)dst = h;
}

// ---------------- prep: gather bias f16 [h][q(224)][key(800)] ----------------
__global__ void prep_bias(const float* __restrict__ biases, const int* __restrict__ idxs,
                          f16* __restrict__ biasT, int n_off) {
    int tid = blockIdx.x * 256 + threadIdx.x;   // 8*224*800
    int h = tid / (NQP * NKEYP);
    int rem = tid - h * (NQP * NKEYP);
    int q = rem / NKEYP;
    int key = rem - q * NKEYP;
    float v = 0.f;
    if (q < NQ && key < NKEY) v = biases[h * n_off + idxs[q * NKEY + key]];
    biasT[tid] = (f16)v;
}

// ---------------- register-A GEMM, k-major W ----------------
// MODE 0: kv  : MF=2 (wave=32 rows), NCP=5, grid (784, 2)
//               A f32 [100352][256] -> K f16 [1024][800][16] + V^T f16 [1024][64][800]
// MODE 1: q   : MF=1, A f32 subsampled -> q f16 [1024][224][16]   (grid.y = 2)
// MODE 2: proj: MF=1, A f16 [25088][512] -> out f32 [25088][384]  (grid.y = 2)
template <int MODE>
__global__ __launch_bounds__(256) void gemm_reg(const void* __restrict__ Ap,
                                                const f16* __restrict__ Wt,
                                                const float* __restrict__ sc,
                                                const float* __restrict__ sh,
                                                void* __restrict__ OutA,
                                                f16* __restrict__ OutV) {
    constexpr int K  = (MODE == 2) ? 512 : 256;
    constexpr int KS = K / 32;
    constexpr int MF = (MODE == 0) ? 2 : 1;    // rows per wave = 16*MF
    constexpr int NT = (MODE == 0) ? 640 : (MODE == 1 ? 128 : 384);
    constexpr int NCP = (MODE == 0) ? 5 : (MODE == 1 ? 1 : 3);   // chunks per block

    const int t = threadIdx.x;
    const int lane = t & 63, wid = t >> 6;
    const int fr = lane & 15, kg = lane >> 4;
    const int m0 = blockIdx.x * (64 * MF);
    const int nb0 = blockIdx.y * (NCP * 64);
    const int wrow0 = m0 + wid * (16 * MF);

    // ---- A fragments into registers ----
    f16x8 af[MF][KS];
#pragma unroll
    for (int mf = 0; mf < MF; ++mf) {
        const int mrow = wrow0 + mf * 16 + fr;
        size_t arow;
        if constexpr (MODE == 1) {
            int b = mrow / 196, nn = mrow - b * 196;
            arow = (size_t)b * 784 + (nn / 14) * 56 + (nn % 14) * 2;
        } else {
            arow = (size_t)mrow;
        }
#pragma unroll
        for (int ks = 0; ks < KS; ++ks) {
            if constexpr (MODE == 2) {
                af[mf][ks] = *(const f16x8*)((const f16*)Ap + arow * K + ks * 32 + kg * 8);
            } else {
                const float* a = (const float*)Ap + arow * 256 + ks * 32 + kg * 8;
                fvec4 v0 = *(const fvec4*)a;
                fvec4 v1 = *(const fvec4*)(a + 4);
                f16x8 hv;
                hv[0] = (f16)v0[0]; hv[1] = (f16)v0[1]; hv[2] = (f16)v0[2]; hv[3] = (f16)v0[3];
                hv[4] = (f16)v1[0]; hv[5] = (f16)v1[1]; hv[6] = (f16)v1[2]; hv[7] = (f16)v1[3];
                af[mf][ks] = hv;
            }
        }
    }

    const int rg = kg * 4;
    for (int c = 0; c < NCP; ++c) {
        const int n0c = nb0 + c * 64;
        f32x4 acc[MF][4];
#pragma unroll
        for (int i = 0; i < MF; ++i)
#pragma unroll
            for (int j = 0; j < 4; ++j) acc[i][j] = (f32x4){0.f, 0.f, 0.f, 0.f};

#pragma unroll
        for (int ks = 0; ks < KS; ++ks) {
            f16x8 bfr[4];
#pragma unroll
            for (int nf = 0; nf < 4; ++nf)
                bfr[nf] = *(const f16x8*)(Wt + ((size_t)(ks * 4 + kg) * NT + n0c + nf * 16 + fr) * 8);
#pragma unroll
            for (int mf = 0; mf < MF; ++mf)
#pragma unroll
                for (int nf = 0; nf < 4; ++nf)
                    acc[mf][nf] = mfma16(af[mf][ks], bfr[nf], acc[mf][nf]);
        }

        // ---- epilogue ----
#pragma unroll
        for (int mf = 0; mf < MF; ++mf) {
            const int mbase = wrow0 + mf * 16 + rg;   // 4 consecutive output rows
#pragma unroll
            for (int nf = 0; nf < 4; ++nf) {
                const int n = n0c + nf * 16 + fr;
                const float scn = sc[n], shn = sh[n];
                if constexpr (MODE == 0) {
                    const int b = mbase / 784;
                    const int nn = mbase - b * 784;      // %4==0, 4-row group in one b
                    const int hd = n / 80;
                    const int cc = n - hd * 80;
                    const size_t bh = (size_t)(b * 8 + hd);
                    if (cc < 16) {
#pragma unroll
                        for (int r = 0; r < 4; ++r) {
                            float y = acc[mf][nf][r] * scn + shn;
                            ((f16*)OutA)[(bh * NKEYP + nn + r) * 16 + cc] = (f16)y;
                        }
                    } else {
                        f16x4 pv;
#pragma unroll
                        for (int r = 0; r < 4; ++r) pv[r] = (f16)(acc[mf][nf][r] * scn + shn);
                        *(f16x4*)(OutV + (bh * 64 + (cc - 16)) * NKEYP + nn) = pv;
                    }
                } else if constexpr (MODE == 1) {
                    const int b = mbase / 196;
                    const int nn = mbase - b * 196;
                    const int hd = n >> 4, cc = n & 15;
                    const size_t bh = (size_t)(b * 8 + hd);
#pragma unroll
                    for (int r = 0; r < 4; ++r) {
                        float y = acc[mf][nf][r] * scn + shn;
                        ((f16*)OutA)[(bh * NQP + nn + r) * 16 + cc] = (f16)y;
                    }
                } else {
#pragma unroll
                    for (int r = 0; r < 4; ++r) {
                        float y = acc[mf][nf][r] * scn + shn;
                        ((float*)OutA)[(size_t)(mbase + r) * 384 + n] = y;
                    }
                }
            }
        }
    }
}

// ---------------- fused attention: block = (b,h), 7 waves = 7 q-tiles ----------------
__global__ __launch_bounds__(448) void attn_fused(const f16* __restrict__ kb,
                                                  const f16* __restrict__ vtb,
                                                  const f16* __restrict__ qw,
                                                  const f16* __restrict__ biasT,
                                                  f16* __restrict__ ao) {
    const int bh = blockIdx.x;
    const int b = bh >> 3, h = bh & 7;
    const int wid = threadIdx.x >> 6;      // q-tile 0..6
    const int lane = threadIdx.x & 63;
    const int l31 = lane & 31;
    const int hh = lane >> 5;
    const int q0 = wid * 32;

    const f16* kp = kb + (size_t)bh * (NKEYP * 16);
    const f16* vp = vtb + (size_t)bh * (64 * NKEYP) + (size_t)l31 * NKEYP;
    const f16x8 bq = *(const f16x8*)(qw + ((size_t)bh * NQP + q0 + l31) * 16 + hh * 8);
    const f16* bbq = biasT + ((size_t)h * NQP + (q0 + l31)) * NKEYP;

    float mrun = -1e30f;
    float lsum = 0.f;
    f32x16 o0 = z16(), o1 = z16();

    for (int key0 = 0; key0 < NKEY; key0 += 32) {
        f16x8 ak = *(const f16x8*)(kp + (size_t)(key0 + l31) * 16 + hh * 8);
        f32x16 s = mfma32(ak, bq, z16());
        const bool tail = (key0 + 32) > NKEY;
        f16x4 bw[4];
#pragma unroll
        for (int g = 0; g < 4; ++g)
            bw[g] = *(const f16x4*)(bbq + key0 + g * 8 + hh * 4);
        float p[16];
        float cmax = -3.0e38f;
#pragma unroll
        for (int r = 0; r < 16; ++r) {
            const int cr = (r & 3) + ((r >> 2) << 3) + (hh << 2);
            float sv = s[r] * 0.25f + (float)bw[r >> 2][r & 3];
            if (tail && (key0 + cr) >= NKEY) sv = -1e30f;
            p[r] = sv;
            cmax = fmaxf(cmax, sv);
        }
        cmax = fmaxf(cmax, __shfl_xor(cmax, 32));
        if (__any(cmax > mrun + 8.f)) {          // defer-max
            float mnew = fmaxf(mrun, cmax);
            float f = __expf(mrun - mnew);
            mrun = mnew;
            lsum *= f;
#pragma unroll
            for (int r = 0; r < 16; ++r) {
                const int cr = (r & 3) + ((r >> 2) << 3) + (hh << 2);
                float fr2 = __shfl(f, cr);
                o0[r] *= fr2;
                o1[r] *= fr2;
            }
        }
        float psum = 0.f;
#pragma unroll
        for (int r = 0; r < 16; ++r) {
            p[r] = __expf(p[r] - mrun);
            psum += p[r];
        }
        lsum += psum;
        unsigned g0l = pk2(p[0], p[1]),   g0h = pk2(p[2], p[3]);
        unsigned g1l = pk2(p[4], p[5]),   g1h = pk2(p[6], p[7]);
        unsigned g2l = pk2(p[8], p[9]),   g2h = pk2(p[10], p[11]);
        unsigned g3l = pk2(p[12], p[13]), g3h = pk2(p[14], p[15]);
        __builtin_amdgcn_s_setprio(1);
#pragma unroll
        for (int sH = 0; sH < 2; ++sH) {
            unsigned self_lo = sH ? (hh ? g3l : g2l) : (hh ? g1l : g0l);
            unsigned self_hi = sH ? (hh ? g3h : g2h) : (hh ? g1h : g0h);
            unsigned tx_lo   = sH ? (hh ? g2l : g3l) : (hh ? g0l : g1l);
            unsigned tx_hi   = sH ? (hh ? g2h : g3h) : (hh ? g0h : g1h);
            unsigned rx_lo = __shfl_xor(tx_lo, 32);
            unsigned rx_hi = __shfl_xor(tx_hi, 32);
            uint4v w;
            w[0] = hh ? rx_lo : self_lo;
            w[1] = hh ? rx_hi : self_hi;
            w[2] = hh ? self_lo : rx_lo;
            w[3] = hh ? self_hi : rx_hi;
            f16x8 pa = __builtin_bit_cast(f16x8, w);
            const f16* vrow = vp + key0 + sH * 16 + hh * 8;
            f16x8 bv0 = *(const f16x8*)(vrow);
            f16x8 bv1 = *(const f16x8*)(vrow + 32 * NKEYP);
            o0 = mfma32(pa, bv0, o0);
            o1 = mfma32(pa, bv1, o1);
        }
        __builtin_amdgcn_s_setprio(0);
    }
    lsum += __shfl_xor(lsum, 32);
    const float inv = 1.0f / lsum;
#pragma unroll
    for (int r = 0; r < 16; ++r) {
        const int cr = (r & 3) + ((r >> 2) << 3) + (hh << 2);
        const float iq = __shfl(inv, cr);
        const int qg = q0 + cr;
        if (qg < NQ) {
            float v0 = o0[r] * iq, v1 = o1[r] * iq;
            float h0 = v0 * fminf(fmaxf(v0 + 3.f, 0.f), 6.f) * (1.f / 6.f);
            float h1 = v1 * fminf(fmaxf(v1 + 3.f, 0.f), 6.f) * (1.f / 6.f);
            f16* dst = ao + ((size_t)b * NQ + qg) * 512 + h * 64 + l31;
            dst[0] = (f16)h0;
            dst[32] = (f16)h1;
        }
    }
}

// ---------------- launch ----------------
extern "C" void kernel_launch(void* const* d_in, const int* in_sizes, int n_in,
                              void* d_out, int out_size, void* d_ws, size_t ws_size,
                              hipStream_t stream) {
    (void)n_in; (void)out_size; (void)ws_size;
    const float* hidden = (const float*)d_in[0];
    const float* w_kv   = (const float*)d_in[1];
    const float* w_q    = (const float*)d_in[6];
    const float* w_p    = (const float*)d_in[11];
    const float* biases = (const float*)d_in[16];
    const int*   idxs   = (const int*)d_in[17];
    const int n_off = in_sizes[16] / 8;

    char* ws = (char*)d_ws;
    const size_t OFF_K  = 0;                       // 26,214,400
    const size_t OFF_V  = 26214400;                // 104,857,600
    const size_t OFF_Q  = 131072000;               //   7,340,032
    const size_t OFF_AO = 138412032;               //  25,690,112
    const size_t OFF_BT = 164102144;               //   2,867,200
    const size_t OFF_W  = 166969344;               //     786,432
    const size_t OFF_SC = 167755776;               //       9,216
    f16*   kbuf  = (f16*)(ws + OFF_K);
    f16*   vbuf  = (f16*)(ws + OFF_V);
    f16*   qbuf  = (f16*)(ws + OFF_Q);
    f16*   aobuf = (f16*)(ws + OFF_AO);
    f16*   btbuf = (f16*)(ws + OFF_BT);
    f16*   wf16  = (f16*)(ws + OFF_W);
    float* scbuf = (float*)(ws + OFF_SC);

    prep_scales_all<<<5, 256, 0, stream>>>(
        (const float*)d_in[2], (const float*)d_in[3], (const float*)d_in[4], (const float*)d_in[5],
        (const float*)d_in[7], (const float*)d_in[8], (const float*)d_in[9], (const float*)d_in[10],
        (const float*)d_in[12], (const float*)d_in[13], (const float*)d_in[14], (const float*)d_in[15],
        scbuf);
    conv_w<<<192, 256, 0, stream>>>(w_kv, w_q, w_p, wf16);
    prep_bias<<<5600, 256, 0, stream>>>(biases, idxs, btbuf, n_off);
    hipMemsetAsync(qbuf, 0, (size_t)1024 * NQP * 16 * 2, stream);  // zero q pad rows
    gemm_reg<0><<<dim3(784, 2), 256, 0, stream>>>(hidden, wf16, scbuf, scbuf + 640, kbuf, vbuf);
    gemm_reg<1><<<dim3(392, 2), 256, 0, stream>>>(hidden, wf16 + 163840, scbuf + 1280, scbuf + 1408, qbuf, nullptr);
    attn_fused<<<1024, 448, 0, stream>>>(kbuf, vbuf, qbuf, btbuf, aobuf);
    gemm_reg<2><<<dim3(392, 2), 256, 0, stream>>>(aobuf, wf16 + 196608, scbuf + 1536, scbuf + 1920, d_out, nullptr);
}